// Round 8
// baseline (421.507 us; speedup 1.0000x reference)
//
#include <hip/hip_runtime.h>
#include <math.h>

typedef __attribute__((ext_vector_type(8)))  short          short8;
typedef __attribute__((ext_vector_type(8)))  unsigned short ushort8;
typedef __attribute__((ext_vector_type(8)))  _Float16       half8;
typedef __attribute__((ext_vector_type(16))) float          f32x16;

#define Bb 16
#define Cc 256
#define Tt 2048

#define LOG2E 1.4426950408889634f

// ---- workspace layout (bytes) ----
#define WH_OFF    0u                         // ushort [320][256] bf16-hi of W
#define WL_OFF    163840u                    // ushort [320][256] bf16-lo of W
#define BALL_OFF  327680u                    // fp32 [320]
#define QTF_OFF   328960u                    // ushort [16][2048][32] fp16 bits, [t][c]  (Q pre-scaled by log2e)
#define KTF_OFF   (QTF_OFF + 2097152u)
#define VBF_OFF   (KTF_OFF + 2097152u)       // ushort [16][256][2048] bf16 bits, [c][t]

__device__ __forceinline__ unsigned short f2bf(float f) {
  union { float f; unsigned u; } v; v.f = f;
  unsigned r = v.u + 0x7fffu + ((v.u >> 16) & 1u);   // RNE
  return (unsigned short)(r >> 16);
}
__device__ __forceinline__ float bf2f(unsigned short h) {
  union { unsigned u; float f; } v; v.u = ((unsigned)h) << 16;
  return v.f;
}
__device__ __forceinline__ unsigned short f2h(float f) {
  union { _Float16 h; unsigned short u; } v; v.h = (_Float16)f;
  return v.u;
}

// ---------------------------------------------------------------------------
// pack: W -> bf16 hi/lo planes [320][256] (+ bias fp32[320]).
// ---------------------------------------------------------------------------
__global__ __launch_bounds__(256) void pack_kernel(
    const float* __restrict__ Wq, const float* __restrict__ bq,
    const float* __restrict__ Wk, const float* __restrict__ bk,
    const float* __restrict__ Wv, const float* __restrict__ bv,
    char* ws) {
  unsigned short* WH = (unsigned short*)(ws + WH_OFF);
  unsigned short* WL = (unsigned short*)(ws + WL_OFF);
  float* ball = (float*)(ws + BALL_OFF);
  int o = blockIdx.x, c = threadIdx.x;
  float v;
  if (o < 32)      v = Wq[o * 256 + c];
  else if (o < 64) v = Wk[(o - 32) * 256 + c];
  else             v = Wv[(o - 64) * 256 + c];
  unsigned short hb = f2bf(v);
  WH[o * 256 + c] = hb;
  WL[o * 256 + c] = f2bf(v - bf2f(hb));
  if (c == 0) ball[o] = (o < 32) ? bq[o] : (o < 64 ? bk[o - 32] : bv[o - 64]);
}

// ---------------------------------------------------------------------------
// proj v2 (unchanged from round 5): t-tile 32, grid (64,16), 4 blocks/CU.
// Q epilogue pre-scales by log2e (attn uses native exp2).
// ---------------------------------------------------------------------------
__global__ __launch_bounds__(256, 4) void proj_kernel(
    const float* __restrict__ x, char* ws) {
  __shared__ __align__(16) float xs[128 * 32];              // 16 KB
  __shared__ __align__(16) unsigned short xth[32 * 136];    // 8.5 KB
  __shared__ __align__(16) unsigned short xtl[32 * 136];    // 8.5 KB

  const unsigned short* WH = (const unsigned short*)(ws + WH_OFF);
  const unsigned short* WL = (const unsigned short*)(ws + WL_OFF);
  const float* ball = (const float*)(ws + BALL_OFF);
  unsigned short* Qtf = (unsigned short*)(ws + QTF_OFF);
  unsigned short* Ktf = (unsigned short*)(ws + KTF_OFF);
  unsigned short* Vbf = (unsigned short*)(ws + VBF_OFF);

  const int b   = blockIdx.y;
  const int t0  = blockIdx.x * 32;
  const int tid = threadIdx.x;
  const int w    = tid >> 6;
  const int lane = tid & 63;
  const int m    = lane & 31;
  const int hh   = lane >> 5;

  const float* xb = x + ((size_t)b * 256) * 2048 + t0;

  f32x16 acc[4];                 // w<2: acc[0]=QK tile; w>=2: 4 V tiles
  #pragma unroll
  for (int j = 0; j < 4; ++j)
    #pragma unroll
    for (int r = 0; r < 16; ++r) acc[j][r] = 0.f;

  #pragma unroll
  for (int r = 0; r < 4; ++r) {
    int idx = r * 256 + tid;
    int c = idx >> 3, f = idx & 7;
    *(float4*)&xs[c * 32 + 4 * f] = *(const float4*)&xb[(size_t)c * 2048 + 4 * f];
  }
  __syncthreads();

  const int cb = (w * 2 + hh) * 16;   // this thread's convert c-base (0..112)

  #pragma unroll
  for (int half = 0; half < 2; ++half) {
    #pragma unroll
    for (int g = 0; g < 2; ++g) {
      ushort8 h8, l8;
      #pragma unroll
      for (int j = 0; j < 8; ++j) {
        float v = xs[(cb + g * 8 + j) * 32 + m];
        unsigned short hb = f2bf(v);
        h8[j] = hb;
        l8[j] = f2bf(v - bf2f(hb));
      }
      *(ushort8*)&xth[m * 136 + cb + g * 8] = h8;
      *(ushort8*)&xtl[m * 136 + cb + g * 8] = l8;
    }
    __syncthreads();

    float4 pre[4];
    if (half == 0) {
      #pragma unroll
      for (int r = 0; r < 4; ++r) {
        int idx = r * 256 + tid;
        int c = idx >> 3, f = idx & 7;
        pre[r] = *(const float4*)&xb[(size_t)(128 + c) * 2048 + 4 * f];
      }
    }

    #pragma unroll
    for (int kk = 0; kk < 8; ++kk) {
      const int kl = kk * 16 + 8 * hh;
      const int kg = half * 128 + kl;
      short8 bh = *(const short8*)&xth[m * 136 + kl];
      if (w < 2) {
        short8 bl = *(const short8*)&xtl[m * 136 + kl];
        short8 ah = *(const short8*)&WH[(size_t)(32 * w + m) * 256 + kg];
        short8 al = *(const short8*)&WL[(size_t)(32 * w + m) * 256 + kg];
        acc[0] = __builtin_amdgcn_mfma_f32_32x32x16_bf16(ah, bh, acc[0], 0, 0, 0);
        acc[0] = __builtin_amdgcn_mfma_f32_32x32x16_bf16(ah, bl, acc[0], 0, 0, 0);
        acc[0] = __builtin_amdgcn_mfma_f32_32x32x16_bf16(al, bh, acc[0], 0, 0, 0);
      } else {
        #pragma unroll
        for (int j = 0; j < 4; ++j) {
          short8 av = *(const short8*)&WH[(size_t)(64 + 32 * (4 * (w - 2) + j) + m) * 256 + kg];
          acc[j] = __builtin_amdgcn_mfma_f32_32x32x16_bf16(av, bh, acc[j], 0, 0, 0);
        }
      }
    }

    if (half == 0) {
      #pragma unroll
      for (int r = 0; r < 4; ++r) {
        int idx = r * 256 + tid;
        int c = idx >> 3, f = idx & 7;
        *(float4*)&xs[c * 32 + 4 * f] = pre[r];
      }
      __syncthreads();
    }
  }

  if (w < 2) {
    unsigned short* pt = (w == 0) ? Qtf : Ktf;
    const float qs = (w == 0) ? LOG2E : 1.0f;
    const int tcol = t0 + m;
    #pragma unroll
    for (int r = 0; r < 16; ++r) {
      int orow = (r & 3) + 8 * (r >> 2) + 4 * hh;
      float v = (acc[0][r] + ball[32 * w + orow]) * qs;
      pt[((size_t)b * 2048 + tcol) * 32 + orow] = f2h(v);
    }
  } else {
    #pragma unroll
    for (int j = 0; j < 4; ++j) {
      const int vob = 64 + 32 * (4 * (w - 2) + j);
      #pragma unroll
      for (int r = 0; r < 16; ++r) {
        int orow = (r & 3) + 8 * (r >> 2) + 4 * hh;
        int o = vob + orow;
        float v = acc[j][r] + ball[o];
        Vbf[((size_t)b * 256 + (o - 64)) * 2048 + t0 + m] = f2bf(v);
      }
    }
  }
}

// ---------------------------------------------------------------------------
// attn v10 = r4 kernel (proven 73.4 us) with ONE change: single Vs buffer
// (32 KB) + a second barrier after PV, instead of double-buffered Vs.
// LDS 80 -> 48 KB  =>  3 blocks/CU (12 waves/CU, +50% TLP of the kind r4
// proved works: independent blocks at different phases fill each other's
// stalls). r7 showed bigger blocks don't deliver TLP (one 512-thread block
// per CU, barrier-coupled); more independent 256-thread blocks is the
// mechanism that does. Index maps / staging / exp chain / epilogue verbatim
// from r4. __launch_bounds__(256,3) caps VGPR ~170 (kernel needs ~124).
// Iter: land Vs<-vpre | prefetch K,V(i+1) | QK+exp->Ps | bar1 | PV | bar2.
// ---------------------------------------------------------------------------
#define ATTN_ITER(PS, KC0, KC1, KN0, KN1, SBN, GUARD)                           \
  {                                                                             \
    _Pragma("unroll")                                                           \
    for (int r = 0; r < 8; ++r) {                                               \
      int c = r * 32 + vc;                                                      \
      *(ushort8*)&Vs[c * 64 + (((vk + c) & 7) << 3)] = vpre[r];                 \
    }                                                                           \
    if (GUARD) {                                                                \
      KN0 = *(const half8*)&Kt[((size_t)b * 2048 + (SBN) + 32 * u + m) * 32 + 8 * hh];      \
      KN1 = *(const half8*)&Kt[((size_t)b * 2048 + (SBN) + 32 * u + m) * 32 + 16 + 8 * hh]; \
      _Pragma("unroll")                                                         \
      for (int r = 0; r < 8; ++r) {                                             \
        int c = r * 32 + vc;                                                    \
        vpre[r] = *(const ushort8*)&Vg[(size_t)c * 2048 + (SBN) + vk * 8];      \
      }                                                                         \
    }                                                                           \
    {                                                                           \
      f32x16 qacc;                                                              \
      _Pragma("unroll")                                                         \
      for (int r = 0; r < 16; ++r) qacc[r] = 0.f;                               \
      qacc = __builtin_amdgcn_mfma_f32_32x32x16_f16(qf0, KC0, qacc, 0, 0, 0);   \
      qacc = __builtin_amdgcn_mfma_f32_32x32x16_f16(qf1, KC1, qacc, 0, 0, 0);   \
      _Pragma("unroll")                                                         \
      for (int r = 0; r < 16; ++r) {                                            \
        float e = exp2f(qacc[r]);                                               \
        unsigned short hb = f2bf(e);                                            \
        sacc[r] += bf2f(hb);                                                    \
        int qq = 32 * n + (r & 3) + 8 * (r >> 2) + 4 * hh;                      \
        PS[qq * 64 + (((scu + qq) & 7) << 3) + sco] = hb;                       \
      }                                                                         \
    }                                                                           \
    __syncthreads();                                                            \
    __builtin_amdgcn_s_setprio(1);                                              \
    _Pragma("unroll")                                                           \
    for (int ks = 0; ks < 4; ++ks) {                                            \
      const int uu = 2 * ks + hh;                                               \
      short8 pp0 = *(const short8*)&PS[m * 64 + (((uu + m) & 7) << 3)];         \
      short8 pp1 = *(const short8*)&PS[(32 + m) * 64 + (((uu + m) & 7) << 3)];  \
      short8 vv0 = *(const short8*)&Vs[c0 * 64 + (((uu + c0) & 7) << 3)];       \
      short8 vv1 = *(const short8*)&Vs[c1 * 64 + (((uu + c1) & 7) << 3)];       \
      pacc[0][0] = __builtin_amdgcn_mfma_f32_32x32x16_bf16(vv0, pp0, pacc[0][0], 0, 0, 0); \
      pacc[0][1] = __builtin_amdgcn_mfma_f32_32x32x16_bf16(vv1, pp0, pacc[0][1], 0, 0, 0); \
      pacc[1][0] = __builtin_amdgcn_mfma_f32_32x32x16_bf16(vv0, pp1, pacc[1][0], 0, 0, 0); \
      pacc[1][1] = __builtin_amdgcn_mfma_f32_32x32x16_bf16(vv1, pp1, pacc[1][1], 0, 0, 0); \
    }                                                                           \
    __builtin_amdgcn_s_setprio(0);                                              \
    __syncthreads();                                                            \
  }

__global__ __launch_bounds__(256, 3) void attn_kernel(
    const float* __restrict__ x, const char* __restrict__ ws,
    float* __restrict__ out) {
  __shared__ __align__(16) unsigned short Vs[256 * 64];    // 32 KB (single)
  __shared__ __align__(16) unsigned short PsA[64 * 64];    // 8 KB
  __shared__ __align__(16) unsigned short PsB[64 * 64];    // 8 KB  (total 48 KB)

  const unsigned short* Qt = (const unsigned short*)(ws + QTF_OFF);
  const unsigned short* Kt = (const unsigned short*)(ws + KTF_OFF);

  const int id = blockIdx.x;
  const int b  = ((id & 7) << 1) | ((id >> 3) & 1);   // 2 batches per XCD
  const int qt = id >> 4;
  const int t0 = qt * 64;
  const int tid  = threadIdx.x;
  const int w    = tid >> 6;
  const int lane = tid & 63;
  const int m    = lane & 31;
  const int hh   = lane >> 5;
  const int n    = w >> 1;       // q-tile for QK
  const int u    = w & 1;        // s-tile for QK
  const int vk   = tid & 7, vc = tid >> 3;
  const int c0   = 32 * w + m, c1 = 32 * (w + 4) + m;
  const int sc   = 32 * u + m, scu = sc >> 3, sco = sc & 7;

  const unsigned short* Vg =
      (const unsigned short*)(ws + VBF_OFF) + (size_t)b * 256 * 2048;

  // persistent Q frags; K frags tile 0; V tile 0 into vpre
  half8 qf0 = *(const half8*)&Qt[((size_t)b * 2048 + t0 + 32 * n + m) * 32 + 8 * hh];
  half8 qf1 = *(const half8*)&Qt[((size_t)b * 2048 + t0 + 32 * n + m) * 32 + 16 + 8 * hh];
  half8 ka0 = *(const half8*)&Kt[((size_t)b * 2048 + 32 * u + m) * 32 + 8 * hh];
  half8 ka1 = *(const half8*)&Kt[((size_t)b * 2048 + 32 * u + m) * 32 + 16 + 8 * hh];
  half8 kb0 = ka0, kb1 = ka1;
  ushort8 vpre[8];
  #pragma unroll
  for (int r = 0; r < 8; ++r) {
    int c = r * 32 + vc;
    vpre[r] = *(const ushort8*)&Vg[(size_t)c * 2048 + vk * 8];
  }

  f32x16 pacc[2][2];
  #pragma unroll
  for (int a = 0; a < 2; ++a)
    #pragma unroll
    for (int d = 0; d < 2; ++d)
      #pragma unroll
      for (int r = 0; r < 16; ++r) pacc[a][d][r] = 0.f;
  float sacc[16];
  #pragma unroll
  for (int r = 0; r < 16; ++r) sacc[r] = 0.f;

  for (int j = 0; j < 16; ++j) {
    const int sb1 = j * 128 + 64;
    const int sb2 = j * 128 + 128;
    ATTN_ITER(PsA, ka0, ka1, kb0, kb1, sb1, true)            // s-tile 2j
    ATTN_ITER(PsB, kb0, kb1, ka0, ka1, sb2, (j < 15))        // s-tile 2j+1
  }

  // ---- row sums (alias retired Ps buffers) ----
  float* sums = (float*)PsA;   // [64][2]
  float* invs = (float*)PsB;   // [64]
  #pragma unroll
  for (int r = 0; r < 16; ++r) {
    float v = sacc[r];
    #pragma unroll
    for (int off = 1; off < 32; off <<= 1) v += __shfl_xor(v, off, 64);
    if (m == 0) sums[(32 * n + (r & 3) + 8 * (r >> 2) + 4 * hh) * 2 + u] = v;
  }
  __syncthreads();
  if (tid < 64) invs[tid] = 1.0f / (sums[tid * 2] + sums[tid * 2 + 1]);
  __syncthreads();

  // ---- epilogue: out = pacc/sum + x, coalesced along t (col = q) ----
  const float inv0 = invs[m], inv1 = invs[32 + m];
  #pragma unroll
  for (int nn = 0; nn < 2; ++nn) {
    const float inv = nn ? inv1 : inv0;
    const int q = 32 * nn + m;
    #pragma unroll
    for (int mi = 0; mi < 2; ++mi) {
      const int cbase = 32 * (w + 4 * mi);
      #pragma unroll
      for (int r = 0; r < 16; ++r) {
        int c = cbase + (r & 3) + 8 * (r >> 2) + 4 * hh;
        size_t a = ((size_t)b * 256 + c) * 2048 + t0 + q;
        out[a] = pacc[nn][mi][r] * inv + x[a];
      }
    }
  }
}

// ---------------------------------------------------------------------------
extern "C" void kernel_launch(void* const* d_in, const int* in_sizes, int n_in,
                              void* d_out, int out_size, void* d_ws, size_t ws_size,
                              hipStream_t stream) {
  const float* x  = (const float*)d_in[0];
  const float* Wq = (const float*)d_in[1];
  const float* bq = (const float*)d_in[2];
  const float* Wk = (const float*)d_in[3];
  const float* bk = (const float*)d_in[4];
  const float* Wv = (const float*)d_in[5];
  const float* bv = (const float*)d_in[6];
  char* ws = (char*)d_ws;

  pack_kernel<<<320, 256, 0, stream>>>(Wq, bq, Wk, bk, Wv, bv, ws);
  proj_kernel<<<dim3(64, 16), 256, 0, stream>>>(x, ws);
  attn_kernel<<<512, 256, 0, stream>>>(x, ws, (float*)d_out);
}

// Round 9
// 178.526 us; speedup vs baseline: 2.3610x; 2.3610x over previous
//
#include <hip/hip_runtime.h>
#include <math.h>

typedef __attribute__((ext_vector_type(8)))  short          short8;
typedef __attribute__((ext_vector_type(8)))  unsigned short ushort8;
typedef __attribute__((ext_vector_type(8)))  _Float16       half8;
typedef __attribute__((ext_vector_type(16))) float          f32x16;

#define Bb 16
#define Cc 256
#define Tt 2048

#define LOG2E 1.4426950408889634f

// ---- workspace layout (bytes) ----
#define WH_OFF    0u                         // ushort [320][256] bf16-hi of W
#define WL_OFF    163840u                    // ushort [320][256] bf16-lo of W
#define BALL_OFF  327680u                    // fp32 [320]
#define QTF_OFF   328960u                    // ushort [16][2048][32] fp16 bits, [t][c]  (Q pre-scaled by log2e)
#define KTF_OFF   (QTF_OFF + 2097152u)
#define VBF_OFF   (KTF_OFF + 2097152u)       // ushort [16][256][2048] bf16 bits, [c][t]

__device__ __forceinline__ unsigned short f2bf(float f) {
  union { float f; unsigned u; } v; v.f = f;
  unsigned r = v.u + 0x7fffu + ((v.u >> 16) & 1u);   // RNE
  return (unsigned short)(r >> 16);
}
__device__ __forceinline__ float bf2f(unsigned short h) {
  union { unsigned u; float f; } v; v.u = ((unsigned)h) << 16;
  return v.f;
}
__device__ __forceinline__ unsigned short f2h(float f) {
  union { _Float16 h; unsigned short u; } v; v.h = (_Float16)f;
  return v.u;
}

// ---------------------------------------------------------------------------
// pack: W -> bf16 hi/lo planes [320][256] (+ bias fp32[320]).
// ---------------------------------------------------------------------------
__global__ __launch_bounds__(256) void pack_kernel(
    const float* __restrict__ Wq, const float* __restrict__ bq,
    const float* __restrict__ Wk, const float* __restrict__ bk,
    const float* __restrict__ Wv, const float* __restrict__ bv,
    char* ws) {
  unsigned short* WH = (unsigned short*)(ws + WH_OFF);
  unsigned short* WL = (unsigned short*)(ws + WL_OFF);
  float* ball = (float*)(ws + BALL_OFF);
  int o = blockIdx.x, c = threadIdx.x;
  float v;
  if (o < 32)      v = Wq[o * 256 + c];
  else if (o < 64) v = Wk[(o - 32) * 256 + c];
  else             v = Wv[(o - 64) * 256 + c];
  unsigned short hb = f2bf(v);
  WH[o * 256 + c] = hb;
  WL[o * 256 + c] = f2bf(v - bf2f(hb));
  if (c == 0) ball[o] = (o < 32) ? bq[o] : (o < 64 ? bk[o - 32] : bv[o - 64]);
}

// ---------------------------------------------------------------------------
// proj v2 (unchanged from round 5): t-tile 32, grid (64,16), 4 blocks/CU.
// Q epilogue pre-scales by log2e (attn uses native exp2).
// ---------------------------------------------------------------------------
__global__ __launch_bounds__(256, 4) void proj_kernel(
    const float* __restrict__ x, char* ws) {
  __shared__ __align__(16) float xs[128 * 32];              // 16 KB
  __shared__ __align__(16) unsigned short xth[32 * 136];    // 8.5 KB
  __shared__ __align__(16) unsigned short xtl[32 * 136];    // 8.5 KB

  const unsigned short* WH = (const unsigned short*)(ws + WH_OFF);
  const unsigned short* WL = (const unsigned short*)(ws + WL_OFF);
  const float* ball = (const float*)(ws + BALL_OFF);
  unsigned short* Qtf = (unsigned short*)(ws + QTF_OFF);
  unsigned short* Ktf = (unsigned short*)(ws + KTF_OFF);
  unsigned short* Vbf = (unsigned short*)(ws + VBF_OFF);

  const int b   = blockIdx.y;
  const int t0  = blockIdx.x * 32;
  const int tid = threadIdx.x;
  const int w    = tid >> 6;
  const int lane = tid & 63;
  const int m    = lane & 31;
  const int hh   = lane >> 5;

  const float* xb = x + ((size_t)b * 256) * 2048 + t0;

  f32x16 acc[4];                 // w<2: acc[0]=QK tile; w>=2: 4 V tiles
  #pragma unroll
  for (int j = 0; j < 4; ++j)
    #pragma unroll
    for (int r = 0; r < 16; ++r) acc[j][r] = 0.f;

  #pragma unroll
  for (int r = 0; r < 4; ++r) {
    int idx = r * 256 + tid;
    int c = idx >> 3, f = idx & 7;
    *(float4*)&xs[c * 32 + 4 * f] = *(const float4*)&xb[(size_t)c * 2048 + 4 * f];
  }
  __syncthreads();

  const int cb = (w * 2 + hh) * 16;   // this thread's convert c-base (0..112)

  #pragma unroll
  for (int half = 0; half < 2; ++half) {
    #pragma unroll
    for (int g = 0; g < 2; ++g) {
      ushort8 h8, l8;
      #pragma unroll
      for (int j = 0; j < 8; ++j) {
        float v = xs[(cb + g * 8 + j) * 32 + m];
        unsigned short hb = f2bf(v);
        h8[j] = hb;
        l8[j] = f2bf(v - bf2f(hb));
      }
      *(ushort8*)&xth[m * 136 + cb + g * 8] = h8;
      *(ushort8*)&xtl[m * 136 + cb + g * 8] = l8;
    }
    __syncthreads();

    float4 pre[4];
    if (half == 0) {
      #pragma unroll
      for (int r = 0; r < 4; ++r) {
        int idx = r * 256 + tid;
        int c = idx >> 3, f = idx & 7;
        pre[r] = *(const float4*)&xb[(size_t)(128 + c) * 2048 + 4 * f];
      }
    }

    #pragma unroll
    for (int kk = 0; kk < 8; ++kk) {
      const int kl = kk * 16 + 8 * hh;
      const int kg = half * 128 + kl;
      short8 bh = *(const short8*)&xth[m * 136 + kl];
      if (w < 2) {
        short8 bl = *(const short8*)&xtl[m * 136 + kl];
        short8 ah = *(const short8*)&WH[(size_t)(32 * w + m) * 256 + kg];
        short8 al = *(const short8*)&WL[(size_t)(32 * w + m) * 256 + kg];
        acc[0] = __builtin_amdgcn_mfma_f32_32x32x16_bf16(ah, bh, acc[0], 0, 0, 0);
        acc[0] = __builtin_amdgcn_mfma_f32_32x32x16_bf16(ah, bl, acc[0], 0, 0, 0);
        acc[0] = __builtin_amdgcn_mfma_f32_32x32x16_bf16(al, bh, acc[0], 0, 0, 0);
      } else {
        #pragma unroll
        for (int j = 0; j < 4; ++j) {
          short8 av = *(const short8*)&WH[(size_t)(64 + 32 * (4 * (w - 2) + j) + m) * 256 + kg];
          acc[j] = __builtin_amdgcn_mfma_f32_32x32x16_bf16(av, bh, acc[j], 0, 0, 0);
        }
      }
    }

    if (half == 0) {
      #pragma unroll
      for (int r = 0; r < 4; ++r) {
        int idx = r * 256 + tid;
        int c = idx >> 3, f = idx & 7;
        *(float4*)&xs[c * 32 + 4 * f] = pre[r];
      }
      __syncthreads();
    }
  }

  if (w < 2) {
    unsigned short* pt = (w == 0) ? Qtf : Ktf;
    const float qs = (w == 0) ? LOG2E : 1.0f;
    const int tcol = t0 + m;
    #pragma unroll
    for (int r = 0; r < 16; ++r) {
      int orow = (r & 3) + 8 * (r >> 2) + 4 * hh;
      float v = (acc[0][r] + ball[32 * w + orow]) * qs;
      pt[((size_t)b * 2048 + tcol) * 32 + orow] = f2h(v);
    }
  } else {
    #pragma unroll
    for (int j = 0; j < 4; ++j) {
      const int vob = 64 + 32 * (4 * (w - 2) + j);
      #pragma unroll
      for (int r = 0; r < 16; ++r) {
        int orow = (r & 3) + 8 * (r >> 2) + 4 * hh;
        int o = vob + orow;
        float v = acc[j][r] + ball[o];
        Vbf[((size_t)b * 256 + (o - 64)) * 2048 + t0 + m] = f2bf(v);
      }
    }
  }
}

// ---------------------------------------------------------------------------
// attn v11 = r8's single-Vs structure (correctness proven) with the register
// budget fixed: __launch_bounds__(256, 2) — the ONLY no-spill setting ever
// measured on this kernel (r4: 124 VGPR, clean). launch_bounds caps regs,
// it does NOT limit residency upward: with 48 KB LDS the HW fits
// floor(160/48) = 3 blocks/CU (12 waves/CU), and 124 VGPR <= the 128-reg
// step allows 4 waves/SIMD — so LDS is the binding limit at 3 blocks/CU.
// r8's (256,3) asked the ALLOCATOR for occupancy and got 84 VGPR + 780 MB
// of spill traffic; this asks the HARDWARE, which just schedules the 3rd
// block. Iter: land Vs | prefetch K,V(i+1) | QK+exp->Ps | bar | PV | bar.
// ---------------------------------------------------------------------------
#define ATTN_ITER(PS, KC0, KC1, KN0, KN1, SBN, GUARD)                           \
  {                                                                             \
    _Pragma("unroll")                                                           \
    for (int r = 0; r < 8; ++r) {                                               \
      int c = r * 32 + vc;                                                      \
      *(ushort8*)&Vs[c * 64 + (((vk + c) & 7) << 3)] = vpre[r];                 \
    }                                                                           \
    if (GUARD) {                                                                \
      KN0 = *(const half8*)&Kt[((size_t)b * 2048 + (SBN) + 32 * u + m) * 32 + 8 * hh];      \
      KN1 = *(const half8*)&Kt[((size_t)b * 2048 + (SBN) + 32 * u + m) * 32 + 16 + 8 * hh]; \
      _Pragma("unroll")                                                         \
      for (int r = 0; r < 8; ++r) {                                             \
        int c = r * 32 + vc;                                                    \
        vpre[r] = *(const ushort8*)&Vg[(size_t)c * 2048 + (SBN) + vk * 8];      \
      }                                                                         \
    }                                                                           \
    {                                                                           \
      f32x16 qacc;                                                              \
      _Pragma("unroll")                                                         \
      for (int r = 0; r < 16; ++r) qacc[r] = 0.f;                               \
      qacc = __builtin_amdgcn_mfma_f32_32x32x16_f16(qf0, KC0, qacc, 0, 0, 0);   \
      qacc = __builtin_amdgcn_mfma_f32_32x32x16_f16(qf1, KC1, qacc, 0, 0, 0);   \
      _Pragma("unroll")                                                         \
      for (int r = 0; r < 16; ++r) {                                            \
        float e = exp2f(qacc[r]);                                               \
        unsigned short hb = f2bf(e);                                            \
        sacc[r] += bf2f(hb);                                                    \
        int qq = 32 * n + (r & 3) + 8 * (r >> 2) + 4 * hh;                      \
        PS[qq * 64 + (((scu + qq) & 7) << 3) + sco] = hb;                       \
      }                                                                         \
    }                                                                           \
    __syncthreads();                                                            \
    __builtin_amdgcn_s_setprio(1);                                              \
    _Pragma("unroll")                                                           \
    for (int ks = 0; ks < 4; ++ks) {                                            \
      const int uu = 2 * ks + hh;                                               \
      short8 pp0 = *(const short8*)&PS[m * 64 + (((uu + m) & 7) << 3)];         \
      short8 pp1 = *(const short8*)&PS[(32 + m) * 64 + (((uu + m) & 7) << 3)];  \
      short8 vv0 = *(const short8*)&Vs[c0 * 64 + (((uu + c0) & 7) << 3)];       \
      short8 vv1 = *(const short8*)&Vs[c1 * 64 + (((uu + c1) & 7) << 3)];       \
      pacc[0][0] = __builtin_amdgcn_mfma_f32_32x32x16_bf16(vv0, pp0, pacc[0][0], 0, 0, 0); \
      pacc[0][1] = __builtin_amdgcn_mfma_f32_32x32x16_bf16(vv1, pp0, pacc[0][1], 0, 0, 0); \
      pacc[1][0] = __builtin_amdgcn_mfma_f32_32x32x16_bf16(vv0, pp1, pacc[1][0], 0, 0, 0); \
      pacc[1][1] = __builtin_amdgcn_mfma_f32_32x32x16_bf16(vv1, pp1, pacc[1][1], 0, 0, 0); \
    }                                                                           \
    __builtin_amdgcn_s_setprio(0);                                              \
    __syncthreads();                                                            \
  }

__global__ __launch_bounds__(256, 2) void attn_kernel(
    const float* __restrict__ x, const char* __restrict__ ws,
    float* __restrict__ out) {
  __shared__ __align__(16) unsigned short Vs[256 * 64];    // 32 KB (single)
  __shared__ __align__(16) unsigned short PsA[64 * 64];    // 8 KB
  __shared__ __align__(16) unsigned short PsB[64 * 64];    // 8 KB  (total 48 KB)

  const unsigned short* Qt = (const unsigned short*)(ws + QTF_OFF);
  const unsigned short* Kt = (const unsigned short*)(ws + KTF_OFF);

  const int id = blockIdx.x;
  const int b  = ((id & 7) << 1) | ((id >> 3) & 1);   // 2 batches per XCD
  const int qt = id >> 4;
  const int t0 = qt * 64;
  const int tid  = threadIdx.x;
  const int w    = tid >> 6;
  const int lane = tid & 63;
  const int m    = lane & 31;
  const int hh   = lane >> 5;
  const int n    = w >> 1;       // q-tile for QK
  const int u    = w & 1;        // s-tile for QK
  const int vk   = tid & 7, vc = tid >> 3;
  const int c0   = 32 * w + m, c1 = 32 * (w + 4) + m;
  const int sc   = 32 * u + m, scu = sc >> 3, sco = sc & 7;

  const unsigned short* Vg =
      (const unsigned short*)(ws + VBF_OFF) + (size_t)b * 256 * 2048;

  // persistent Q frags; K frags tile 0; V tile 0 into vpre
  half8 qf0 = *(const half8*)&Qt[((size_t)b * 2048 + t0 + 32 * n + m) * 32 + 8 * hh];
  half8 qf1 = *(const half8*)&Qt[((size_t)b * 2048 + t0 + 32 * n + m) * 32 + 16 + 8 * hh];
  half8 ka0 = *(const half8*)&Kt[((size_t)b * 2048 + 32 * u + m) * 32 + 8 * hh];
  half8 ka1 = *(const half8*)&Kt[((size_t)b * 2048 + 32 * u + m) * 32 + 16 + 8 * hh];
  half8 kb0 = ka0, kb1 = ka1;
  ushort8 vpre[8];
  #pragma unroll
  for (int r = 0; r < 8; ++r) {
    int c = r * 32 + vc;
    vpre[r] = *(const ushort8*)&Vg[(size_t)c * 2048 + vk * 8];
  }

  f32x16 pacc[2][2];
  #pragma unroll
  for (int a = 0; a < 2; ++a)
    #pragma unroll
    for (int d = 0; d < 2; ++d)
      #pragma unroll
      for (int r = 0; r < 16; ++r) pacc[a][d][r] = 0.f;
  float sacc[16];
  #pragma unroll
  for (int r = 0; r < 16; ++r) sacc[r] = 0.f;

  for (int j = 0; j < 16; ++j) {
    const int sb1 = j * 128 + 64;
    const int sb2 = j * 128 + 128;
    ATTN_ITER(PsA, ka0, ka1, kb0, kb1, sb1, true)            // s-tile 2j
    ATTN_ITER(PsB, kb0, kb1, ka0, ka1, sb2, (j < 15))        // s-tile 2j+1
  }

  // ---- row sums (alias retired Ps buffers) ----
  float* sums = (float*)PsA;   // [64][2]
  float* invs = (float*)PsB;   // [64]
  #pragma unroll
  for (int r = 0; r < 16; ++r) {
    float v = sacc[r];
    #pragma unroll
    for (int off = 1; off < 32; off <<= 1) v += __shfl_xor(v, off, 64);
    if (m == 0) sums[(32 * n + (r & 3) + 8 * (r >> 2) + 4 * hh) * 2 + u] = v;
  }
  __syncthreads();
  if (tid < 64) invs[tid] = 1.0f / (sums[tid * 2] + sums[tid * 2 + 1]);
  __syncthreads();

  // ---- epilogue: out = pacc/sum + x, coalesced along t (col = q) ----
  const float inv0 = invs[m], inv1 = invs[32 + m];
  #pragma unroll
  for (int nn = 0; nn < 2; ++nn) {
    const float inv = nn ? inv1 : inv0;
    const int q = 32 * nn + m;
    #pragma unroll
    for (int mi = 0; mi < 2; ++mi) {
      const int cbase = 32 * (w + 4 * mi);
      #pragma unroll
      for (int r = 0; r < 16; ++r) {
        int c = cbase + (r & 3) + 8 * (r >> 2) + 4 * hh;
        size_t a = ((size_t)b * 256 + c) * 2048 + t0 + q;
        out[a] = pacc[nn][mi][r] * inv + x[a];
      }
    }
  }
}

// ---------------------------------------------------------------------------
extern "C" void kernel_launch(void* const* d_in, const int* in_sizes, int n_in,
                              void* d_out, int out_size, void* d_ws, size_t ws_size,
                              hipStream_t stream) {
  const float* x  = (const float*)d_in[0];
  const float* Wq = (const float*)d_in[1];
  const float* bq = (const float*)d_in[2];
  const float* Wk = (const float*)d_in[3];
  const float* bk = (const float*)d_in[4];
  const float* Wv = (const float*)d_in[5];
  const float* bv = (const float*)d_in[6];
  char* ws = (char*)d_ws;

  pack_kernel<<<320, 256, 0, stream>>>(Wq, bq, Wk, bk, Wv, bv, ws);
  proj_kernel<<<dim3(64, 16), 256, 0, stream>>>(x, ws);
  attn_kernel<<<512, 256, 0, stream>>>(x, ws, (float*)d_out);
}